// Round 1
// baseline (31291.269 us; speedup 1.0000x reference)
//
#include <hip/hip_runtime.h>
#include <math.h>

#define NPART 16384
#define TSTEPS 4096
#define NTHR 1024
#define PPT 16   // particles per thread

#if __has_builtin(__builtin_amdgcn_exp2f)
__device__ __forceinline__ float fexp2(float x) { return __builtin_amdgcn_exp2f(x); }
#else
__device__ __forceinline__ float fexp2(float x) { return exp2f(x); }
#endif
#if __has_builtin(__builtin_amdgcn_logf)
__device__ __forceinline__ float flog2(float x) { return __builtin_amdgcn_logf(x); }
#else
__device__ __forceinline__ float flog2(float x) { return log2f(x); }
#endif

// XOR swizzle: bijective involution on [0,16384); makes the strided read-back
// (lane l reads dwords starting at 16*l) exactly 2-way on 32 banks (= free).
__device__ __forceinline__ int swz(int a) { return a ^ ((a >> 4) & 31); }

__device__ __forceinline__ void do_step(
    int t,
    float4 e0, float4 e1, float4 e2, float4 e3, float y, float u,
    float* __restrict__ h,            // [PPT] register array
    float mu, float rho, float sz, float nu, float c3,
    float A2, float B2, float lam, float lconst,
    float* __restrict__ newh,         // LDS [NPART]
    float* __restrict__ wIncl,        // LDS [16]
    float* __restrict__ wS1,          // LDS [16]
    float* __restrict__ wS2,          // LDS [16]
    float* __restrict__ out,
    int tid, int lane, int wv)
{
  float ev[PPT] = { e0.x, e0.y, e0.z, e0.w,
                    e1.x, e1.y, e1.z, e1.w,
                    e2.x, e2.y, e2.z, e2.w,
                    e3.x, e3.y, e3.z, e3.w };
  const float yy = y * y;

  float c[PPT];                 // thread-local inclusive cumsum of weights
  float cum = 0.0f, s1 = 0.0f, s2 = 0.0f;

#pragma unroll
  for (int j = 0; j < PPT; ++j) {
    // AR(1) predict: h = mu + rho*(h-mu) + sz*eps
    float hj = fmaf(rho, h[j] - mu, mu);
    hj = fmaf(sz, ev[j], hj);
    h[j] = hj;
    // unnormalized weight (lconst factored out):
    //   ln w' = (c3-0.5)h + c3 ln(nu) - c3 ln(nu e^h + y^2)
    float P = fexp2(lam * hj);          // e^{h/2}
    float E = P * P;                    // e^{h}
    float M = flog2(fmaf(nu, E, yy));   // log2(nu e^h + y^2)
    float g = fmaf(B2, hj, A2) - c3 * M;
    float wj = fexp2(g);
    cum += wj;
    c[j] = cum;
    s1 = fmaf(wj, hj, s1);              // sum w*h
    s2 = fmaf(wj, P, s2);               // sum w*e^{h/2}
  }

  // wave-level inclusive scan of thread totals
  float xi = cum;
#pragma unroll
  for (int d = 1; d < 64; d <<= 1) {
    float tmp = __shfl_up(xi, d, 64);
    if (lane >= d) xi += tmp;
  }
  // wave-level reductions for s1, s2
#pragma unroll
  for (int d = 1; d < 64; d <<= 1) {
    s1 += __shfl_xor(s1, d, 64);
    s2 += __shfl_xor(s2, d, 64);
  }
  if (lane == 63) wIncl[wv] = xi;
  if (lane == 0)  { wS1[wv] = s1; wS2[wv] = s2; }
  __syncthreads();   // barrier 1

  // Every wave redundantly computes the cross-wave offsets with an IDENTICAL
  // sequential loop -> bitwise-identical prefixes everywhere (exact partition).
  float off = 0.0f, offn = 0.0f, Tot = 0.0f;
#pragma unroll
  for (int v = 0; v < 16; ++v) {
    float tv = wIncl[v];
    off  += (v <  wv) ? tv : 0.0f;
    offn += (v <= wv) ? tv : 0.0f;
    Tot  += tv;
  }

  if (tid == 0) {
    float S1t = 0.0f, S2t = 0.0f;
#pragma unroll
    for (int v = 0; v < 16; ++v) { S1t += wS1[v]; S2t += wS2[v]; }
    // ll = lconst + ln(Tot) - ln(N);  ln(N) = 14*ln2
    float ll = lconst + 0.69314718055994531f * (flog2(Tot) - 14.0f);
    out[t] = ll;
    out[TSTEPS + t] = S1t / Tot;
    out[2 * TSTEPS + t] = S2t / Tot;
  }

  // thread-exclusive prefix (exact bits via shfl of the scanned value)
  float xe = __shfl_up(xi, 1, 64);
  if (lane == 0) xe = 0.0f;
  float ecs = off + xe;                  // this thread's exclusive cumsum
  float eNx = __shfl_down(ecs, 1, 64);   // neighbor's exclusive (exact bits)
  if (lane == 63) eNx = offn;            // next wave's lane0 value, identical bits

  float r = (float)NPART / Tot;

  // output slots owned by this thread: [p0, Cp]
  int p = (int)floorf(fmaf(ecs, r, -u)) + 1;
  if (tid == 0) p = 0;                   // covers u==0 edge; no-op for u>0
  int Cp;
  if (tid == NTHR - 1) Cp = NPART - 1;   // cs[-1] := 1.0 semantics
  else {
    Cp = (int)floorf(fmaf(eNx, r, -u));
    Cp = min(Cp, NPART - 1);
  }

  // systematic-resampling scatter: source j fills slots (b_{j-1}, b_j]
#pragma unroll
  for (int j = 0; j < PPT; ++j) {
    int i1;
    if (j == PPT - 1) i1 = Cp;
    else {
      float bj = ecs + c[j];
      i1 = min(Cp, (int)floorf(fmaf(bj, r, -u)));
    }
    while (p <= i1) { newh[swz(p)] = h[j]; ++p; }
  }
  __syncthreads();   // barrier 2 (scatter visible)

  // read back this thread's resampled slice (swizzled -> 2-way banks = free)
#pragma unroll
  for (int j = 0; j < PPT; ++j) {
    int a = tid * PPT + j;
    h[j] = newh[swz(a)];
  }
}

__global__ __launch_bounds__(NTHR) void bpf_kernel(
    const float* __restrict__ mu_raw, const float* __restrict__ rho_raw,
    const float* __restrict__ lsz_raw, const float* __restrict__ nu_raw,
    const float* __restrict__ y_seq, const float* __restrict__ h_init,
    const float* __restrict__ eps_seq, const float* __restrict__ u_seq,
    float* __restrict__ out)
{
  __shared__ float newh[NPART];   // 64 KB
  __shared__ float wIncl[16];
  __shared__ float wS1[16];
  __shared__ float wS2[16];

  const int tid = threadIdx.x;
  const int lane = tid & 63;
  const int wv = tid >> 6;

  // constrained parameters (match reference transforms)
  const float mu = mu_raw[0];
  const float rho = 1.0f / (1.0f + expf(-rho_raw[0]));
  const float sz = log1pf(expf(lsz_raw[0]));
  const float nu = 2.0f + log1pf(expf(nu_raw[0]));
  const float c3 = 0.5f * (nu + 1.0f);
  const float lconst = lgammaf(0.5f * (nu + 1.0f)) - lgammaf(0.5f * nu)
                     - 0.5f * logf(nu * 3.14159265358979323846f);
  const float L2E = 1.44269504088896340736f;
  const float A2 = c3 * log2f(nu);
  const float B2 = (c3 - 0.5f) * L2E;
  const float lam = 0.5f * L2E;

  // initial particle state -> registers
  float h[PPT];
  {
    const float4* hp = (const float4*)h_init + tid * 4;
    float4 a = hp[0], b = hp[1], cc = hp[2], d = hp[3];
    h[0] = a.x;  h[1] = a.y;  h[2] = a.z;  h[3] = a.w;
    h[4] = b.x;  h[5] = b.y;  h[6] = b.z;  h[7] = b.w;
    h[8] = cc.x; h[9] = cc.y; h[10] = cc.z; h[11] = cc.w;
    h[12] = d.x; h[13] = d.y; h[14] = d.z; h[15] = d.w;
  }

  // software-pipelined eps / y / u (register double buffer A/B)
  float4 ea0, ea1, ea2, ea3, eb0, eb1, eb2, eb3;
  float ya, ua, yb, ub;
  {
    const float4* ep = (const float4*)eps_seq + tid * 4;
    ea0 = ep[0]; ea1 = ep[1]; ea2 = ep[2]; ea3 = ep[3];
    ya = y_seq[0]; ua = u_seq[0];
  }

  for (int t = 0; t < TSTEPS; t += 2) {
    {   // prefetch t+1 into B (t+1 <= TSTEPS-1 always since TSTEPS even)
      const float4* ep = (const float4*)(eps_seq + (size_t)(t + 1) * NPART) + tid * 4;
      eb0 = ep[0]; eb1 = ep[1]; eb2 = ep[2]; eb3 = ep[3];
      yb = y_seq[t + 1]; ub = u_seq[t + 1];
    }
    do_step(t, ea0, ea1, ea2, ea3, ya, ua, h,
            mu, rho, sz, nu, c3, A2, B2, lam, lconst,
            newh, wIncl, wS1, wS2, out, tid, lane, wv);
    if (t + 2 < TSTEPS) {   // prefetch t+2 into A
      const float4* ep = (const float4*)(eps_seq + (size_t)(t + 2) * NPART) + tid * 4;
      ea0 = ep[0]; ea1 = ep[1]; ea2 = ep[2]; ea3 = ep[3];
      ya = y_seq[t + 2]; ua = u_seq[t + 2];
    }
    do_step(t + 1, eb0, eb1, eb2, eb3, yb, ub, h,
            mu, rho, sz, nu, c3, A2, B2, lam, lconst,
            newh, wIncl, wS1, wS2, out, tid, lane, wv);
  }
}

extern "C" void kernel_launch(void* const* d_in, const int* in_sizes, int n_in,
                              void* d_out, int out_size, void* d_ws, size_t ws_size,
                              hipStream_t stream) {
  const float* mu_raw  = (const float*)d_in[0];
  const float* rho_raw = (const float*)d_in[1];
  const float* lsz     = (const float*)d_in[2];
  const float* nu_raw  = (const float*)d_in[3];
  const float* y_seq   = (const float*)d_in[4];
  const float* h_init  = (const float*)d_in[5];
  const float* eps_seq = (const float*)d_in[6];
  const float* u_seq   = (const float*)d_in[7];
  float* out = (float*)d_out;

  bpf_kernel<<<dim3(1), dim3(NTHR), 0, stream>>>(
      mu_raw, rho_raw, lsz, nu_raw, y_seq, h_init, eps_seq, u_seq, out);
}